// Round 2
// baseline (725.803 us; speedup 1.0000x reference)
//
#include <hip/hip_runtime.h>

#define D     3072
#define H1    32
#define H2    32
#define OUTD  10
#define NEG   0.01f
#define KSPL  8              // k-split across waves in a block
#define KPW   (D / KSPL)     // 384 k per wave
#define NCH   (KPW / 16)     // 24 chunks of 16 k

// ---------------------------------------------------------------------------
// Prep: wt2[(oct*32 + j)*384 + k'] = w1[j][oct*384 + k']   (j-major, k-contig)
//       s1[j] = sum_k w1[j][k]
// One s_load_dwordx16 of wt2 then feeds 16 FMAs into a single accumulator.
// ---------------------------------------------------------------------------
__global__ void prep_kernel(const float* __restrict__ w1,
                            float* __restrict__ wt2,
                            float* __restrict__ s1) {
    const int j = blockIdx.x;    // 0..31
    const int t = threadIdx.x;   // 0..255
    float s = 0.f;
    for (int k = t; k < D; k += 256) {
        float v = w1[j * D + k];
        int oct = k / KPW;
        int kk  = k - oct * KPW;
        wt2[(size_t)(oct * H1 + j) * KPW + kk] = v;
        s += v;
    }
    __shared__ float red[256];
    red[t] = s;
    __syncthreads();
    for (int off = 128; off > 0; off >>= 1) {
        if (t < off) red[t] += red[t + off];
        __syncthreads();
    }
    if (t == 0) s1[j] = red[0];
}

// ---------------------------------------------------------------------------
// Fused: rownorm + 3-layer MLP + LeakyReLU, one pass over x.
// Block = 512 thr (8 waves): lane (tid&63) -> row, wave -> k-octant (384 k).
// w is wave-uniform j-major/k-contiguous -> scalar s_load_dwordx16 per 16 FMA.
// Cross-wave reduce: turn-taking accumulation into a 9 KB LDS buffer.
// ---------------------------------------------------------------------------
__global__ __launch_bounds__(512, 4) void fused_kernel(
    const float* __restrict__ x,
    const float* __restrict__ wt2,
    const float* __restrict__ s1,
    const float* __restrict__ b1,
    const float* __restrict__ w2,
    const float* __restrict__ b2,
    const float* __restrict__ w3,
    const float* __restrict__ b3,
    float* __restrict__ out)
{
    const int tid  = threadIdx.x;
    const int lane = tid & 63;
    const int wv   = __builtin_amdgcn_readfirstlane(tid >> 6);  // 0..7, uniform
    const int row  = blockIdx.x * 64 + lane;

    const float4* __restrict__ xp =
        (const float4*)(x + (size_t)row * D + wv * KPW);
    const float*  __restrict__ wb = wt2 + (size_t)(wv * H1) * KPW;

    float acc[H1];
#pragma unroll
    for (int j = 0; j < H1; ++j) acc[j] = 0.f;
    float s = 0.f, ss = 0.f;

    // prefetch chunk 0
    float4 cur0 = xp[0], cur1 = xp[1], cur2 = xp[2], cur3 = xp[3];

    for (int c = 0; c < NCH; ++c) {
        const int cn = (c + 1 < NCH) ? (c + 1) : 0;   // last iter re-reads 0 (harmless)
        float4 n0 = xp[cn * 4 + 0];
        float4 n1 = xp[cn * 4 + 1];
        float4 n2 = xp[cn * 4 + 2];
        float4 n3 = xp[cn * 4 + 3];

        float xv[16] = {cur0.x, cur0.y, cur0.z, cur0.w,
                        cur1.x, cur1.y, cur1.z, cur1.w,
                        cur2.x, cur2.y, cur2.z, cur2.w,
                        cur3.x, cur3.y, cur3.z, cur3.w};
#pragma unroll
        for (int t2 = 0; t2 < 16; ++t2) {
            s += xv[t2];
            ss = fmaf(xv[t2], xv[t2], ss);
        }

        const float* wc = wb + c * 16;    // uniform
#pragma unroll
        for (int j = 0; j < H1; ++j) {
            const float* wj = wc + (size_t)j * KPW;   // uniform, 16 contiguous
#pragma unroll
            for (int t2 = 0; t2 < 16; ++t2)
                acc[j] = fmaf(xv[t2], wj[t2], acc[j]);  // v,v,s,v
        }

        cur0 = n0; cur1 = n1; cur2 = n2; cur3 = n3;
    }

    // ---- cross-wave reduction: turn-taking into 64x36 LDS (9 KB) ----
    __shared__ float red[64 * 36];
    float* slot = &red[lane * 36];
    for (int r = 0; r < KSPL; ++r) {
        if (wv == r) {
            if (r == 0) {
#pragma unroll
                for (int j = 0; j < H1; ++j) slot[j] = acc[j];
                slot[32] = s;
                slot[33] = ss;
            } else {
#pragma unroll
                for (int j = 0; j < H1; ++j) slot[j] += acc[j];
                slot[32] += s;
                slot[33] += ss;
            }
        }
        __syncthreads();
    }

    // ---- epilogue: one wave finishes 64 rows ----
    if (tid < 64) {
        const int r = blockIdx.x * 64 + tid;
        const float* p = &red[tid * 36];
        const float S  = p[32];
        const float SS = p[33];
        const float mean    = S * (1.f / D);
        const float var     = (SS - S * S * (1.f / D)) * (1.f / (D - 1));
        const float inv_std = rsqrtf(var);

        float y1[H1];
#pragma unroll
        for (int j = 0; j < H1; ++j) {
            float v = (p[j] - mean * s1[j]) * inv_std + b1[j];
            y1[j] = (v >= 0.f) ? v : NEG * v;
        }
        float y2[H2];
#pragma unroll
        for (int j = 0; j < H2; ++j) {
            float a = b2[j];
            const float* wr = w2 + j * H1;     // uniform -> s_load
#pragma unroll
            for (int i2 = 0; i2 < H1; ++i2) a = fmaf(wr[i2], y1[i2], a);
            y2[j] = (a >= 0.f) ? a : NEG * a;
        }
#pragma unroll
        for (int j = 0; j < OUTD; ++j) {
            float a = b3[j];
            const float* wr = w3 + j * H2;     // uniform -> s_load
#pragma unroll
            for (int i2 = 0; i2 < H2; ++i2) a = fmaf(wr[i2], y2[i2], a);
            a = (a >= 0.f) ? a : NEG * a;
            out[(size_t)r * OUTD + j] = a;
        }
    }
}

// ---------------------------------------------------------------------------
extern "C" void kernel_launch(void* const* d_in, const int* in_sizes, int n_in,
                              void* d_out, int out_size, void* d_ws, size_t ws_size,
                              hipStream_t stream) {
    const float* x  = (const float*)d_in[0];
    const float* w1 = (const float*)d_in[1];
    const float* b1 = (const float*)d_in[2];
    const float* w2 = (const float*)d_in[3];
    const float* b2 = (const float*)d_in[4];
    const float* w3 = (const float*)d_in[5];
    const float* b3 = (const float*)d_in[6];
    float* out = (float*)d_out;

    const int B = in_sizes[0] / D;           // 32768

    float* wt2 = (float*)d_ws;               // D*H1 floats = 384 KB
    float* s1  = wt2 + (size_t)D * H1;       // +32 floats

    prep_kernel<<<H1, 256, 0, stream>>>(w1, wt2, s1);
    fused_kernel<<<B / 64, 512, 0, stream>>>(x, wt2, s1, b1, w2, b2, w3, b3, out);
}

// Round 3
// 565.221 us; speedup vs baseline: 1.2841x; 1.2841x over previous
//
#include <hip/hip_runtime.h>

#define D      3072
#define H1     32
#define OUTD   10
#define NEG    0.01f
#define KHALF  (D / 2)          // 1536 k per wave
#define NCHUNK (KHALF / 32)     // 48 chunks of 32 k

typedef short s16x8 __attribute__((ext_vector_type(8)));
typedef float f32x4 __attribute__((ext_vector_type(4)));

// fp32 -> bf16, round-to-nearest-even (x is N(0,1): no NaN/Inf handling needed)
static __device__ __forceinline__ short f2bf(float f) {
    unsigned u = __builtin_bit_cast(unsigned, f);
    u += 0x7FFF + ((u >> 16) & 1);
    return (short)(u >> 16);
}

// ---------------------------------------------------------------------------
// Prep 1: s1[j] = sum_k w1[j][k]  (fp32)
// ---------------------------------------------------------------------------
__global__ void prep_s1(const float* __restrict__ w1, float* __restrict__ s1) {
    const int j = blockIdx.x, t = threadIdx.x;
    float s = 0.f;
    for (int k = t; k < D; k += 256) s += w1[j * D + k];
    __shared__ float red[256];
    red[t] = s;
    __syncthreads();
    for (int off = 128; off > 0; off >>= 1) {
        if (t < off) red[t] += red[t + off];
        __syncthreads();
    }
    if (t == 0) s1[j] = red[0];
}

// ---------------------------------------------------------------------------
// Prep 2: pack w1^T into bf16 MFMA B-fragments.
// B[k][n] = w1[n][k].  Frag for (chunk c, half h): lane holds
// B[k = c*32 + (lane>>4)*8 + i][n = 16h + (lane&15)], i=0..7  -> one s16x8.
// Stored at bf[(c*2 + h)*64 + lane].
// ---------------------------------------------------------------------------
__global__ void prep_pack(const float* __restrict__ w1, s16x8* __restrict__ bf) {
    const int c = blockIdx.x;       // 0..95
    const int t = threadIdx.x;      // 0..127
    const int h = t >> 6, lane = t & 63;
    const int n  = h * 16 + (lane & 15);
    const int k0 = c * 32 + (lane >> 4) * 8;
    const float* src = w1 + (size_t)n * D + k0;   // 8 contiguous fp32
    float4 a = ((const float4*)src)[0];
    float4 b = ((const float4*)src)[1];
    s16x8 v;
    v[0] = f2bf(a.x); v[1] = f2bf(a.y); v[2] = f2bf(a.z); v[3] = f2bf(a.w);
    v[4] = f2bf(b.x); v[5] = f2bf(b.y); v[6] = f2bf(b.z); v[7] = f2bf(b.w);
    bf[(size_t)(c * 2 + h) * 64 + lane] = v;
}

// ---------------------------------------------------------------------------
// Fused main: block = 256 thr (4 waves) = 2 row-strips x 2 k-halves.
// Wave: 16 rows x 1536 k. A-frags straight from global fp32 x (+cvt),
// B-frags from packed ws (L2-resident). S/SS in fp32 VALU alongside.
// Epilogue: rownorm algebra + layers 2/3 via LDS.
// ---------------------------------------------------------------------------
__global__ __launch_bounds__(256, 4) void fused_kernel(
    const float* __restrict__ x,
    const s16x8* __restrict__ bf,
    const float* __restrict__ s1,
    const float* __restrict__ b1,
    const float* __restrict__ w2,
    const float* __restrict__ b2,
    const float* __restrict__ w3,
    const float* __restrict__ b3,
    float* __restrict__ out)
{
    const int tid   = threadIdx.x;
    const int lane  = tid & 63;
    const int wv    = __builtin_amdgcn_readfirstlane(tid >> 6);  // 0..3
    const int strip = wv >> 1;        // 0/1: rows [0:16) / [16:32) of block
    const int khalf = wv & 1;         // 0/1: k [0:1536) / [1536:3072)
    const int quad  = lane >> 4;      // 0..3
    const int col   = lane & 15;      // A row m / D col n
    const int row   = blockIdx.x * 32 + strip * 16 + col;

    const float4* xq = (const float4*)(x + (size_t)row * D + khalf * KHALF + quad * 8);
    const s16x8*  bb = bf + (size_t)(khalf * NCHUNK * 2) * 64 + lane;

    f32x4 acc0 = {0.f, 0.f, 0.f, 0.f};
    f32x4 acc1 = {0.f, 0.f, 0.f, 0.f};
    float s = 0.f, ss = 0.f;

    float4 xa = xq[0], xb = xq[1];
    s16x8  bf0 = bb[0], bf1 = bb[64];

    for (int c = 0; c < NCHUNK; ++c) {
        const int cn = (c + 1 < NCHUNK) ? (c + 1) : 0;   // wrap: harmless re-read
        float4 nxa = xq[cn * 8 + 0];
        float4 nxb = xq[cn * 8 + 1];
        s16x8  nb0 = bb[(size_t)(cn * 2 + 0) * 64];
        s16x8  nb1 = bb[(size_t)(cn * 2 + 1) * 64];

        s += xa.x; s += xa.y; s += xa.z; s += xa.w;
        s += xb.x; s += xb.y; s += xb.z; s += xb.w;
        ss = fmaf(xa.x, xa.x, ss); ss = fmaf(xa.y, xa.y, ss);
        ss = fmaf(xa.z, xa.z, ss); ss = fmaf(xa.w, xa.w, ss);
        ss = fmaf(xb.x, xb.x, ss); ss = fmaf(xb.y, xb.y, ss);
        ss = fmaf(xb.z, xb.z, ss); ss = fmaf(xb.w, xb.w, ss);

        s16x8 af;
        af[0] = f2bf(xa.x); af[1] = f2bf(xa.y); af[2] = f2bf(xa.z); af[3] = f2bf(xa.w);
        af[4] = f2bf(xb.x); af[5] = f2bf(xb.y); af[6] = f2bf(xb.z); af[7] = f2bf(xb.w);

        acc0 = __builtin_amdgcn_mfma_f32_16x16x32_bf16(af, bf0, acc0, 0, 0, 0);
        acc1 = __builtin_amdgcn_mfma_f32_16x16x32_bf16(af, bf1, acc1, 0, 0, 0);

        xa = nxa; xb = nxb; bf0 = nb0; bf1 = nb1;
    }

    // reduce S/SS across the 4 quads (same row lives in lanes col, col+16, ...)
    s  += __shfl_xor(s, 16, 64);  s  += __shfl_xor(s, 32, 64);
    ss += __shfl_xor(ss, 16, 64); ss += __shfl_xor(ss, 32, 64);

    __shared__ float pd[2][32][33];     // [khalf][row][n]  (pad 33: no conflicts)
    __shared__ float sbuf[2][32], qbuf[2][32];
    __shared__ float y1buf[32][33];
    __shared__ float y2buf[32][33];

#pragma unroll
    for (int r = 0; r < 4; ++r) {       // D row m = quad*4 + r, col n
        pd[khalf][strip * 16 + quad * 4 + r][col]      = acc0[r];
        pd[khalf][strip * 16 + quad * 4 + r][16 + col] = acc1[r];
    }
    if (lane < 16) {
        sbuf[khalf][strip * 16 + lane] = s;
        qbuf[khalf][strip * 16 + lane] = ss;
    }
    __syncthreads();

    // ---- normalization + layer 1 epilogue: 32 threads, one per row ----
    if (tid < 32) {
        const int r = tid;
        const float S  = sbuf[0][r] + sbuf[1][r];
        const float SS = qbuf[0][r] + qbuf[1][r];
        const float mean    = S * (1.f / D);
        const float var     = (SS - S * S * (1.f / D)) * (1.f / (D - 1));
        const float inv_std = rsqrtf(var);
#pragma unroll
        for (int n = 0; n < H1; ++n) {
            float dot = pd[0][r][n] + pd[1][r][n];
            float v = (dot - mean * s1[n]) * inv_std + b1[n];
            y1buf[r][n] = (v >= 0.f) ? v : NEG * v;
        }
    }
    __syncthreads();

    // ---- layer 2: 256 threads -> (row = t>>3, 4 n's each) ----
    {
        const int r2 = tid >> 3, j0 = (tid & 7) * 4;
#pragma unroll
        for (int jj = 0; jj < 4; ++jj) {
            const int j = j0 + jj;
            float a = b2[j];
            const float4* wv4 = (const float4*)(w2 + j * H1);
#pragma unroll
            for (int i4 = 0; i4 < 8; ++i4) {
                float4 w = wv4[i4];
                a = fmaf(w.x, y1buf[r2][i4 * 4 + 0], a);
                a = fmaf(w.y, y1buf[r2][i4 * 4 + 1], a);
                a = fmaf(w.z, y1buf[r2][i4 * 4 + 2], a);
                a = fmaf(w.w, y1buf[r2][i4 * 4 + 3], a);
            }
            y2buf[r2][j] = (a >= 0.f) ? a : NEG * a;
        }
    }
    __syncthreads();

    // ---- layer 3: 320 tasks over 256 threads ----
    for (int task = tid; task < 32 * OUTD; task += 256) {
        const int r3 = task / OUTD, j = task - r3 * OUTD;
        float a = b3[j];
        const float4* wv4 = (const float4*)(w3 + j * H1);
#pragma unroll
        for (int i4 = 0; i4 < 8; ++i4) {
            float4 w = wv4[i4];
            a = fmaf(w.x, y2buf[r3][i4 * 4 + 0], a);
            a = fmaf(w.y, y2buf[r3][i4 * 4 + 1], a);
            a = fmaf(w.z, y2buf[r3][i4 * 4 + 2], a);
            a = fmaf(w.w, y2buf[r3][i4 * 4 + 3], a);
        }
        a = (a >= 0.f) ? a : NEG * a;
        out[(size_t)(blockIdx.x * 32 + r3) * OUTD + j] = a;
    }
}

// ---------------------------------------------------------------------------
extern "C" void kernel_launch(void* const* d_in, const int* in_sizes, int n_in,
                              void* d_out, int out_size, void* d_ws, size_t ws_size,
                              hipStream_t stream) {
    const float* x  = (const float*)d_in[0];
    const float* w1 = (const float*)d_in[1];
    const float* b1 = (const float*)d_in[2];
    const float* w2 = (const float*)d_in[3];
    const float* b2 = (const float*)d_in[4];
    const float* w3 = (const float*)d_in[5];
    const float* b3 = (const float*)d_in[6];
    float* out = (float*)d_out;

    const int B = in_sizes[0] / D;                 // 32768

    s16x8* bfrag = (s16x8*)d_ws;                   // 96*2*64*16 B = 192 KB
    float* s1    = (float*)d_ws + (96 * 2 * 64 * 4);  // after frags (in floats)

    prep_s1  <<<H1, 256, 0, stream>>>(w1, s1);
    prep_pack<<<96, 128, 0, stream>>>(w1, bfrag);
    fused_kernel<<<B / 32, 256, 0, stream>>>(x, bfrag, s1, b1, w2, b2, w3, b3, out);
}